// Round 1
// 4116.853 us; speedup vs baseline: 2.3584x; 2.3584x over previous
//
#include <hip/hip_runtime.h>

#define TT 128
#define BB 64
#define HH 2048
#define VV 10000
#define VP 10048

typedef __attribute__((ext_vector_type(8))) short s16x8;
typedef __attribute__((ext_vector_type(4))) float f32x4;

#define MFMA(a,b,c) __builtin_amdgcn_mfma_f32_16x16x32_bf16((a),(b),(c),0,0,0)

static __device__ __forceinline__ short f2bf(float x){
  unsigned u = __float_as_uint(x);
  u += 0x7fffu + ((u>>16)&1u);
  return (short)(u>>16);
}
static __device__ __forceinline__ float bf2f(short b){
  return __uint_as_float(((unsigned)(unsigned short)b)<<16);
}

// Swizzled fragment layout for an [N,K] matrix used as MFMA B-operand (or [M,K] as A):
//   idx = ((nt*KC + kc)*64 + lane)*8 + j,  row = nt*16+(lane&15), k = kc*32+(lane>>4)*8+j
// -> a wave's fragment load is 64 lanes x 16B contiguous.

// ---------- split W0 into x-part / h-part, hi/lo bf16, swizzled (KC=64 each) ----------
__global__ __launch_bounds__(256) void k_split_w0(
    const float* __restrict__ W0,
    short* __restrict__ WxHi, short* __restrict__ WxLo,
    short* __restrict__ WhHi, short* __restrict__ WhLo){
  int tid = blockIdx.x*256 + threadIdx.x;     // 2048*512 threads
  int row = tid >> 9;
  int c8  = (tid & 511) << 3;
  const float4* s = (const float4*)(W0 + (size_t)row*4096 + c8);
  float4 f0 = s[0], f1 = s[1];
  float v[8] = {f0.x,f0.y,f0.z,f0.w,f1.x,f1.y,f1.z,f1.w};
  short hs[8], lsv[8];
#pragma unroll
  for(int j=0;j<8;j++){ hs[j]=f2bf(v[j]); lsv[j]=f2bf(v[j]-bf2f(hs[j])); }
  int isH = (c8 >= 2048);
  int k = c8 - (isH ? 2048 : 0);
  short* dh = isH ? WhHi : WxHi;
  short* dl = isH ? WhLo : WxLo;
  int nt = row>>4, kc = k>>5, ln = (row&15) | (((k>>3)&3)<<4);
  size_t base = ((size_t)(nt*64 + kc)*64 + ln)*8;
  *(s16x8*)(dh+base) = *(s16x8*)hs;
  *(s16x8*)(dl+base) = *(s16x8*)lsv;
}

// ---------- split W1 (K=4096, KC=128) ----------
__global__ __launch_bounds__(256) void k_split_w1(
    const float* __restrict__ W1,
    short* __restrict__ WHi, short* __restrict__ WLo){
  int tid = blockIdx.x*256 + threadIdx.x;
  int row = tid >> 9;
  int c8  = (tid & 511) << 3;
  const float4* s = (const float4*)(W1 + (size_t)row*4096 + c8);
  float4 f0 = s[0], f1 = s[1];
  float v[8] = {f0.x,f0.y,f0.z,f0.w,f1.x,f1.y,f1.z,f1.w};
  short hs[8], lsv[8];
#pragma unroll
  for(int j=0;j<8;j++){ hs[j]=f2bf(v[j]); lsv[j]=f2bf(v[j]-bf2f(hs[j])); }
  int nt = row>>4, kc = c8>>5, ln = (row&15) | (((c8>>3)&3)<<4);
  size_t base = ((size_t)(nt*128 + kc)*64 + ln)*8;
  *(s16x8*)(WHi+base) = *(s16x8*)hs;
  *(s16x8*)(WLo+base) = *(s16x8*)lsv;
}

// ---------- Wout -> single bf16, swizzled, zero-padded to 10048 rows ----------
__global__ __launch_bounds__(256) void k_conv_wout(
    const float* __restrict__ Wout, short* __restrict__ Wo){
  int row = blockIdx.x;             // 0..10047
  int k = threadIdx.x << 3;
  short hs[8];
  if(row < VV){
    const float4* s = (const float4*)(Wout + (size_t)row*2048 + k);
    float4 f0 = s[0], f1 = s[1];
    float v[8] = {f0.x,f0.y,f0.z,f0.w,f1.x,f1.y,f1.z,f1.w};
#pragma unroll
    for(int j=0;j<8;j++) hs[j]=f2bf(v[j]);
  } else {
#pragma unroll
    for(int j=0;j<8;j++) hs[j]=0;
  }
  int nt = row>>4, kc = k>>5, ln = (row&15) | (((k>>3)&3)<<4);
  size_t base = ((size_t)(nt*64 + kc)*64 + ln)*8;
  *(s16x8*)(Wo+base) = *(s16x8*)hs;
}

// ---------- init h state from `hidden` input (written to parity-1 buffers) ----------
__global__ __launch_bounds__(256) void k_init(
    const float* __restrict__ hid,
    float* __restrict__ h0f, float* __restrict__ h1f,
    short* __restrict__ h0Hi, short* __restrict__ h0Lo,
    short* __restrict__ h1Hi, short* __restrict__ h1Lo){
  int tid = blockIdx.x*256 + threadIdx.x;   // 32768
  int l = tid >> 14;
  int r = tid & 16383;
  int m = r >> 8;
  int k = (r & 255) << 3;
  const float* s = hid + ((size_t)l*BB + m)*HH + k;
  float v[8];
#pragma unroll
  for(int j=0;j<8;j++) v[j]=s[j];
  float* df = l ? h1f : h0f;
  short* dh = l ? h1Hi : h0Hi;
  short* dl = l ? h1Lo : h0Lo;
#pragma unroll
  for(int j=0;j<8;j++) df[(size_t)m*HH + k + j] = v[j];
  short hs[8], lsv[8];
#pragma unroll
  for(int j=0;j<8;j++){ hs[j]=f2bf(v[j]); lsv[j]=f2bf(v[j]-bf2f(hs[j])); }
  int mt = m>>4, kc = k>>5, ln = (m&15) | (((k>>3)&3)<<4);
  size_t base = ((size_t)(mt*64 + kc)*64 + ln)*8;
  *(s16x8*)(dh+base) = *(s16x8*)hs;
  *(s16x8*)(dl+base) = *(s16x8*)lsv;
}

// ---------- Phase A: P0 = gather(emb)[8192,2048] @ Wx0^T + b0  (hi/lo 3-product) ----------
__global__ __launch_bounds__(256) void k_gemmA(
    const int* __restrict__ toks, const float* __restrict__ emb,
    const short* __restrict__ WxHi, const short* __restrict__ WxLo,
    const float* __restrict__ b0, float* __restrict__ P0){
  __shared__ short aHi[2][2048];
  __shared__ short aLo[2][2048];
  int bx = blockIdx.x, by = blockIdx.y;
  int tid = threadIdx.x, w = tid>>6, ln = tid&63;
  int srow = w*16 + (ln&15);
  int tok = toks[by*64 + srow];
  const float* rowp = emb + (size_t)tok*2048 + ((ln>>4)<<3);
  int nt = bx*4 + w;
  f32x4 acc[4] = {{0,0,0,0},{0,0,0,0},{0,0,0,0},{0,0,0,0}};
  for(int kc=0;kc<64;kc++){
    int p = kc&1;
    const float4* sp = (const float4*)(rowp + kc*32);
    float4 f0 = sp[0], f1 = sp[1];
    float v[8] = {f0.x,f0.y,f0.z,f0.w,f1.x,f1.y,f1.z,f1.w};
    short hs[8], lsv[8];
#pragma unroll
    for(int j=0;j<8;j++){ hs[j]=f2bf(v[j]); lsv[j]=f2bf(v[j]-bf2f(hs[j])); }
    *(s16x8*)&aHi[p][tid*8] = *(s16x8*)hs;
    *(s16x8*)&aLo[p][tid*8] = *(s16x8*)lsv;
    __syncthreads();
    size_t bidx = ((size_t)(nt*64 + kc)*64 + ln)*8;
    s16x8 bh = *(const s16x8*)(WxHi + bidx);
    s16x8 bl = *(const s16x8*)(WxLo + bidx);
#pragma unroll
    for(int mt=0;mt<4;mt++){
      s16x8 ah = *(const s16x8*)&aHi[p][(mt*64+ln)*8];
      s16x8 al = *(const s16x8*)&aLo[p][(mt*64+ln)*8];
      acc[mt] = MFMA(ah,bh,acc[mt]);
      acc[mt] = MFMA(al,bh,acc[mt]);
      acc[mt] = MFMA(ah,bl,acc[mt]);
    }
  }
  int nl = ln&15;
  int n = bx*64 + w*16 + nl;
  float bias = b0[n];
  int r0 = (ln>>4)*4;
#pragma unroll
  for(int mt=0;mt<4;mt++){
#pragma unroll
    for(int r=0;r<4;r++){
      int m = by*64 + mt*16 + r0 + r;
      P0[(size_t)m*HH + n] = acc[mt][r] + bias;
    }
  }
}

// ---------- fused per-step kernel: blocks 0..127 do layer0 step t,
//            blocks 128..255 do layer1 step t-1 (layer-lag pipelining).
//   l0: h0(t)   = tanh(P0[t]   + h0(t-1) @ Wh0^T)
//   l1: h1(t-1) = tanh([h0(t-1), h1(t-2)] @ W1^T + b1)
//   Both depend ONLY on the previous kernel's outputs -> run concurrently.
__global__ __launch_bounds__(512,2) void k_step(
    int t,
    const short* __restrict__ h0rH, const short* __restrict__ h0rL,   // h0(t-1)
    const short* __restrict__ h1rH, const short* __restrict__ h1rL,   // h1(t-2)
    const short* __restrict__ WhHi, const short* __restrict__ WhLo,
    const short* __restrict__ W1Hi, const short* __restrict__ W1Lo,
    const float* __restrict__ P0t, const float* __restrict__ b1,
    float* __restrict__ h0f, short* __restrict__ h0wH, short* __restrict__ h0wL,  // h0(t)
    float* __restrict__ h1f, short* __restrict__ h1wH, short* __restrict__ h1wL,  // h1(t-1)
    short* __restrict__ H1t){
  __shared__ float red[8][64][16];
  int bid = blockIdx.x;
  int isL1 = (bid >= 128);
  if(isL1 ? (t==0) : (t==TT)) return;
  int nt = isL1 ? (bid - 128) : bid;
  int tid = threadIdx.x, w = tid>>6, ln = tid&63;
  f32x4 acc[4] = {{0,0,0,0},{0,0,0,0},{0,0,0,0},{0,0,0,0}};

  if(!isL1){
    // K=2048 split over 8 waves: kc = w*8 + i, i<8
    int kc0 = w*8;
    size_t bbase = ((size_t)(nt*64 + kc0)*64 + ln)*8;
    size_t abase = ((size_t)kc0*64 + ln)*8;       // + mt*32768 + i*512
    s16x8 bh = *(const s16x8*)(WhHi + bbase);
    s16x8 bl = *(const s16x8*)(WhLo + bbase);
    s16x8 ah[4], al[4];
#pragma unroll
    for(int mt=0;mt<4;mt++){
      ah[mt] = *(const s16x8*)(h0rH + abase + mt*32768);
      al[mt] = *(const s16x8*)(h0rL + abase + mt*32768);
    }
#pragma unroll
    for(int i=0;i<8;i++){
      s16x8 bh2, bl2, ah2[4], al2[4];
      if(i<7){                       // prefetch next kc while MFMAs run
        size_t bb = bbase + (size_t)(i+1)*512;
        size_t ab = abase + (size_t)(i+1)*512;
        bh2 = *(const s16x8*)(WhHi + bb);
        bl2 = *(const s16x8*)(WhLo + bb);
#pragma unroll
        for(int mt=0;mt<4;mt++){
          ah2[mt] = *(const s16x8*)(h0rH + ab + mt*32768);
          al2[mt] = *(const s16x8*)(h0rL + ab + mt*32768);
        }
      }
#pragma unroll
      for(int mt=0;mt<4;mt++){
        acc[mt] = MFMA(ah[mt],bh,acc[mt]);
        acc[mt] = MFMA(al[mt],bh,acc[mt]);
        acc[mt] = MFMA(ah[mt],bl,acc[mt]);
      }
      if(i<7){
        bh = bh2; bl = bl2;
#pragma unroll
        for(int mt=0;mt<4;mt++){ ah[mt]=ah2[mt]; al[mt]=al2[mt]; }
      }
    }
  } else {
    // K=4096 split over 8 waves: kcg = w*16 + i, i<16; A = [h0(t-1), h1(t-2)]
    const short* AH = (w<4) ? h0rH : h1rH;
    const short* AL = (w<4) ? h0rL : h1rL;
    int kcg0 = w*16;
    int kcl0 = (w&3)*16;
    size_t bbase = ((size_t)(nt*128 + kcg0)*64 + ln)*8;
    size_t abase = ((size_t)kcl0*64 + ln)*8;
    s16x8 bh = *(const s16x8*)(W1Hi + bbase);
    s16x8 bl = *(const s16x8*)(W1Lo + bbase);
    s16x8 ah[4], al[4];
#pragma unroll
    for(int mt=0;mt<4;mt++){
      ah[mt] = *(const s16x8*)(AH + abase + mt*32768);
      al[mt] = *(const s16x8*)(AL + abase + mt*32768);
    }
#pragma unroll
    for(int i=0;i<16;i++){
      s16x8 bh2, bl2, ah2[4], al2[4];
      if(i<15){
        size_t bb = bbase + (size_t)(i+1)*512;
        size_t ab = abase + (size_t)(i+1)*512;
        bh2 = *(const s16x8*)(W1Hi + bb);
        bl2 = *(const s16x8*)(W1Lo + bb);
#pragma unroll
        for(int mt=0;mt<4;mt++){
          ah2[mt] = *(const s16x8*)(AH + ab + mt*32768);
          al2[mt] = *(const s16x8*)(AL + ab + mt*32768);
        }
      }
#pragma unroll
      for(int mt=0;mt<4;mt++){
        acc[mt] = MFMA(ah[mt],bh,acc[mt]);
        acc[mt] = MFMA(al[mt],bh,acc[mt]);
        acc[mt] = MFMA(ah[mt],bl,acc[mt]);
      }
      if(i<15){
        bh = bh2; bl = bl2;
#pragma unroll
        for(int mt=0;mt<4;mt++){ ah[mt]=ah2[mt]; al[mt]=al2[mt]; }
      }
    }
  }

#pragma unroll
  for(int mt=0;mt<4;mt++)
#pragma unroll
    for(int r=0;r<4;r++)
      red[w][mt*16 + (ln>>4)*4 + r][ln&15] = acc[mt][r];
  __syncthreads();
  int m = tid>>3, nl0 = (tid&7)*2;
#pragma unroll
  for(int i2=0;i2<2;i2++){
    int nl = nl0 + i2, n = nt*16 + nl;
    float s = 0.f;
#pragma unroll
    for(int ww=0;ww<8;ww++) s += red[ww][m][nl];
    float val;
    if(!isL1) val = tanhf(s + P0t[(size_t)m*HH + n]);
    else      val = tanhf(s + b1[n]);
    short hi = f2bf(val), lo = f2bf(val - bf2f(hi));
    int mt = m>>4, kc = n>>5, ln2 = (m&15) | (((n>>3)&3)<<4), j = n&7;
    size_t idx = ((size_t)(mt*64 + kc)*64 + ln2)*8 + j;
    if(!isL1){
      h0f[(size_t)m*HH + n] = val;
      h0wH[idx] = hi; h0wL[idx] = lo;
    } else {
      h1f[(size_t)m*HH + n] = val;
      h1wH[idx] = hi; h1wL[idx] = lo;
      H1t[idx] = hi;
    }
  }
}

// ---------- Phase C: logits = H1[8192,2048] @ Wout^T + bout  (plain bf16) ----------
__global__ __launch_bounds__(256) void k_gemmC(
    const short* __restrict__ H1s, const short* __restrict__ Wo,
    const float* __restrict__ bout, float* __restrict__ outp){
  __shared__ short aB[2][2048];
  int bx = blockIdx.x, by = blockIdx.y;
  int tid = threadIdx.x, w = tid>>6, ln = tid&63;
  int nt = bx*4 + w;
  f32x4 acc[4] = {{0,0,0,0},{0,0,0,0},{0,0,0,0},{0,0,0,0}};
  for(int kc=0;kc<64;kc++){
    int p = kc&1;
    s16x8 av = *(const s16x8*)(H1s + ((size_t)((by*4+w)*64 + kc)*64 + ln)*8);
    *(s16x8*)&aB[p][tid*8] = av;
    __syncthreads();
    size_t bidx = ((size_t)(nt*64 + kc)*64 + ln)*8;
    s16x8 bh = *(const s16x8*)(Wo + bidx);
#pragma unroll
    for(int mt=0;mt<4;mt++){
      s16x8 ah = *(const s16x8*)&aB[p][(mt*64+ln)*8];
      acc[mt] = MFMA(ah,bh,acc[mt]);
    }
  }
  int n = bx*64 + w*16 + (ln&15);
  if(n < VV){
    float bias = bout[n];
    int r0 = (ln>>4)*4;
#pragma unroll
    for(int mt=0;mt<4;mt++){
#pragma unroll
      for(int r=0;r<4;r++){
        int m = by*64 + mt*16 + r0 + r;
        outp[(size_t)m*VV + n] = acc[mt][r] + bias;
      }
    }
  }
}

// ---------- final hidden copy ----------
__global__ __launch_bounds__(256) void k_final(
    const float* __restrict__ h0f, const float* __restrict__ h1f,
    float* __restrict__ dst){
  int tid = blockIdx.x*256 + threadIdx.x;    // 65536 threads, float4 each
  const float4* s = (tid < 32768) ? (const float4*)h0f : (const float4*)h1f;
  ((float4*)dst)[tid] = s[tid & 32767];
}

extern "C" void kernel_launch(void* const* d_in, const int* in_sizes, int n_in,
                              void* d_out, int out_size, void* d_ws, size_t ws_size,
                              hipStream_t stream){
  const int*   toks = (const int*)d_in[0];
  const float* hid  = (const float*)d_in[1];
  const float* emb  = (const float*)d_in[2];
  const float* W0   = (const float*)d_in[3];
  const float* b0   = (const float*)d_in[4];
  const float* W1   = (const float*)d_in[5];
  const float* b1   = (const float*)d_in[6];
  const float* Wout = (const float*)d_in[7];
  const float* bout = (const float*)d_in[8];
  float* out = (float*)d_out;

  char* ws = (char*)d_ws;
  size_t off = 0;
  auto take = [&](size_t bytes)->void*{
    void* r = ws + off; off += (bytes + 255) & ~(size_t)255; return r; };

  short* WxHi = (short*)take((size_t)2048*2048*2);
  short* WxLo = (short*)take((size_t)2048*2048*2);
  short* WhHi = (short*)take((size_t)2048*2048*2);
  short* WhLo = (short*)take((size_t)2048*2048*2);
  short* W1Hi = (short*)take((size_t)2048*4096*2);
  short* W1Lo = (short*)take((size_t)2048*4096*2);
  short* Wo   = (short*)take((size_t)VP*2048*2);
  float* P0   = (float*)take((size_t)8192*2048*4);
  short* H1s  = (short*)take((size_t)8192*2048*2);
  float *h0F[2], *h1F[2];
  short *h0Hi[2], *h0Lo[2], *h1Hi[2], *h1Lo[2];
  for(int i=0;i<2;i++){
    h0F[i]  = (float*)take((size_t)64*2048*4);
    h1F[i]  = (float*)take((size_t)64*2048*4);
    h0Hi[i] = (short*)take((size_t)64*2048*2);
    h0Lo[i] = (short*)take((size_t)64*2048*2);
    h1Hi[i] = (short*)take((size_t)64*2048*2);
    h1Lo[i] = (short*)take((size_t)64*2048*2);
  }

  k_split_w0<<<4096,256,0,stream>>>(W0, WxHi,WxLo,WhHi,WhLo);
  k_split_w1<<<4096,256,0,stream>>>(W1, W1Hi,W1Lo);
  k_conv_wout<<<VP,256,0,stream>>>(Wout, Wo);
  // init state lives in parity-1 buffers:
  //   h0(s) is stored in h0*[s&1]  -> h0(-1) => index 1
  //   h1(s) is stored in h1*[s&1]  -> h1(-1) => index 1
  k_init<<<128,256,0,stream>>>(hid, h0F[1],h1F[1], h0Hi[1],h0Lo[1], h1Hi[1],h1Lo[1]);
  k_gemmA<<<dim3(32,128),256,0,stream>>>(toks, emb, WxHi, WxLo, b0, P0);

  // K_t computes h0(t) [l0 blocks] and h1(t-1) [l1 blocks]; t = 0..128.
  for(int t=0;t<=TT;t++){
    int pa = (t-1)&1;            // parity of t-1  (== 1 for t==0)
    int pb = t&1;                // parity of t
    int tp = (t>0) ? (t-1) : 0;  // H1s slot (unused at t==0)
    int tc = (t<TT) ? t : (TT-1);// P0 slot  (unused at t==TT)
    k_step<<<256,512,0,stream>>>(t,
        h0Hi[pa],h0Lo[pa],          // h0(t-1)
        h1Hi[pb],h1Lo[pb],          // h1(t-2)  [(t-2)&1 == t&1]
        WhHi,WhLo, W1Hi,W1Lo,
        P0 + (size_t)tc*64*2048, b1,
        h0F[pb],h0Hi[pb],h0Lo[pb],  // h0(t)
        h1F[pa],h1Hi[pa],h1Lo[pa],  // h1(t-1)
        H1s + (size_t)tp*64*2048);
  }

  k_gemmC<<<dim3(157,128),256,0,stream>>>(H1s, Wo, bout, out);
  // h0(127) -> parity 1; h1(127) -> parity 1 (written by K_128)
  k_final<<<256,256,0,stream>>>(h0F[1], h1F[1], out + (size_t)8192*VV);
}